// Round 6
// baseline (251.218 us; speedup 1.0000x reference)
//
#include <hip/hip_runtime.h>
#include <hip/hip_bf16.h>

typedef __attribute__((ext_vector_type(8))) short short8;
typedef __attribute__((ext_vector_type(4))) float f32x4;
typedef __attribute__((ext_vector_type(4))) unsigned short u16x4;
typedef unsigned short u16;
typedef unsigned int u32;
typedef unsigned long long u64;

#define NB 16
#define NS 512
#define ND 512
#define NH 8
#define NT 8
#define NDK 64
#define NN (NB*NS)
#define SCALE_LOG2E 0.18033688011112042f   // (1/sqrt(64)) * log2(e)
#define BM 128
#define BN 128
#define BKK 64

__device__ __forceinline__ u16 f2bf(float f) {
    __hip_bfloat16 h = __float2bfloat16(f);
    return *reinterpret_cast<u16*>(&h);
}
__device__ __forceinline__ float bf2f(u16 b) {
    u32 u = ((u32)b) << 16;
    return *reinterpret_cast<float*>(&u);
}
__device__ __forceinline__ u32 pk2(float lo, float hi) {
    return (u32)f2bf(lo) | ((u32)f2bf(hi) << 16);
}

typedef const __attribute__((address_space(1))) void* gas_t;
typedef __attribute__((address_space(3))) void* las_t;

__device__ __forceinline__ void gload16(const void* gsrc, void* ldst) {
    __builtin_amdgcn_global_load_lds((gas_t)gsrc, (las_t)ldst, 16, 0, 0);
}

// ================= fused preprocessing =================
// blocks [0,4096): cvt_x ; [4096,6144): cvt_w ; [6144,7168): pack_mask (16 chunks each)
// [7168,7232): per-slice type count (64 slices x 128 tokens)
__global__ __launch_bounds__(256) void pre_all(
    const float* __restrict__ x, const int* __restrict__ xty, const int* __restrict__ mask,
    const float* __restrict__ Wq, const float* __restrict__ Wk,
    const float* __restrict__ Wv, const float* __restrict__ Wa,
    u16* __restrict__ xb,
    u16* __restrict__ Wqt, u16* __restrict__ Wkt, u16* __restrict__ Wvt, u16* __restrict__ Wat,
    u64* __restrict__ maskb, int* __restrict__ scnt)
{
    __shared__ __align__(16) float tile[64][68];
    __shared__ int cnt[NT];
    int bid = blockIdx.x, tid = threadIdx.x;

    if (bid < 4096) {                           // ---- cvt_x ----
        int i = bid * 256 + tid;
        float4 v = reinterpret_cast<const float4*>(x)[i];
        u16x4 o;
        o.x = f2bf(v.x); o.y = f2bf(v.y); o.z = f2bf(v.z); o.w = f2bf(v.w);
        reinterpret_cast<u16x4*>(xb)[i] = o;
    } else if (bid < 6144) {                    // ---- cvt_w (transpose+convert) ----
        int wid = bid - 4096;
        int bx = wid & 7, by = (wid >> 3) & 7, bz = wid >> 6;
        int arr = bz >> 3, t = bz & 7;
        const float* W = (arr == 0 ? Wq : arr == 1 ? Wk : arr == 2 ? Wv : Wa) + ((size_t)t << 18);
        u16* O = (arr == 0 ? Wqt : arr == 1 ? Wkt : arr == 2 ? Wvt : Wat) + ((size_t)t << 18);
        int d0 = bx * 64, h0 = by * 64;
        int tx = tid & 15, ty = tid >> 4;
        #pragma unroll
        for (int i = 0; i < 4; ++i) {
            int r = ty + i * 16;
            float4 v = *reinterpret_cast<const float4*>(&W[(size_t)(d0 + r) * ND + h0 + tx * 4]);
            *reinterpret_cast<float4*>(&tile[r][tx * 4]) = v;
        }
        __syncthreads();
        #pragma unroll
        for (int i = 0; i < 4; ++i) {
            int r = ty + i * 16;
            u16x4 o;
            o.x = f2bf(tile[tx * 4 + 0][r]);
            o.y = f2bf(tile[tx * 4 + 1][r]);
            o.z = f2bf(tile[tx * 4 + 2][r]);
            o.w = f2bf(tile[tx * 4 + 3][r]);
            *reinterpret_cast<u16x4*>(&O[(size_t)(h0 + r) * ND + d0 + tx * 4]) = o;
        }
    } else if (bid < 7168) {                    // ---- pack_mask, grid-stride 16 ----
        int base = (bid - 6144) * 16;
        #pragma unroll
        for (int c = 0; c < 16; ++c) {
            int i = (base + c) * 256 + tid;
            int v = mask[i];
            u64 bal = __ballot(v != 0);
            if ((tid & 63) == 0) maskb[i >> 6] = bal;
        }
    } else {                                    // ---- type count, slice s ----
        int s = bid - 7168;
        if (tid < NT) cnt[tid] = 0;
        __syncthreads();
        if (tid < 128) atomicAdd(&cnt[xty[s * 128 + tid]], 1);
        __syncthreads();
        if (tid < NT) scnt[s * 8 + tid] = cnt[tid];
    }
}

// ================= scatter: build perm / typeoff / tile list (totals from scnt) =================
__global__ __launch_bounds__(256) void scatter_k(
    const int* __restrict__ xty, const int* __restrict__ scnt,
    int* __restrict__ perm, int* __restrict__ typeoff,
    int* __restrict__ tile_type, int* __restrict__ tile_row0, int* __restrict__ ntiles)
{
    __shared__ int base[NT], tot[NT];
    int s = blockIdx.x, tid = threadIdx.x;
    if (tid < NT) {
        int tt = 0;
        for (int ss = 0; ss < 64; ++ss) tt += scnt[ss * 8 + tid];
        tot[tid] = tt;
    }
    __syncthreads();
    if (tid < NT) {
        int off = 0;
        for (int u = 0; u < tid; ++u) off += tot[u];
        base[tid] = off;
    }
    __syncthreads();
    {                                            // += earlier slices' counts (parallel)
        int t = tid & 7;
        for (int ss = tid >> 3; ss < s; ss += 32) atomicAdd(&base[t], scnt[ss * 8 + t]);
    }
    __syncthreads();
    if (tid < 128) {
        int n = s * 128 + tid;
        int t = xty[n];
        int p = atomicAdd(&base[t], 1);
        perm[p] = n;
    }
    if (s == 0 && tid == 0) {
        int acc = 0, nt = 0;
        for (int t = 0; t < NT; ++t) {
            typeoff[t] = acc;
            int c = tot[t];
            for (int r = 0; r < c; r += BM) { tile_type[nt] = t; tile_row0[nt] = acc + r; ++nt; }
            acc += c;
        }
        typeoff[NT] = acc;
        *ntiles = nt;
    }
}

// ================= grouped GEMM qkv: pair-persistent (2 works/block, flat 16-iter pipeline) =================
__global__ __launch_bounds__(256) void qkv_gemm(
    const u16* __restrict__ xb,
    const u16* __restrict__ Wqt, const u16* __restrict__ Wkt, const u16* __restrict__ Wvt,
    const float* __restrict__ bq, const float* __restrict__ bk, const float* __restrict__ bv,
    const int* __restrict__ perm, const int* __restrict__ typeoff,
    const int* __restrict__ tile_type, const int* __restrict__ tile_row0, const int* __restrict__ ntiles,
    u16* __restrict__ qb, u16* __restrict__ kbf, u16* __restrict__ vb)
{
    int p = (blockIdx.x & 7) * 54 + (blockIdx.x >> 3);  // 432 = 8*54, XCD swizzle
    int tile = p / 6;                                    // 6 pairs per tile
    if (tile >= *ntiles) return;
    int pairc = p % 6;
    int proj = pairc >> 1;                               // pair shares proj
    int colbase = (pairc & 1) * 256;                     // covers cols colbase, colbase+128
    int t = tile_type[tile];
    int row0 = tile_row0[tile];
    int rows = typeoff[t + 1] - row0; if (rows > BM) rows = BM;
    const u16* W = (proj == 0 ? Wqt : proj == 1 ? Wkt : Wvt) + ((size_t)t << 18);
    const float* bias = (proj == 0 ? bq : proj == 1 ? bk : bv) + (t << 9);
    u16* outp = proj == 0 ? qb : proj == 1 ? kbf : vb;
    float qscale = proj == 0 ? SCALE_LOG2E : 1.f;

    __shared__ __align__(16) u16 smem[2][2][BM][BKK];    // [buf][A/B]; each buf contiguous 32 KB
    __shared__ int stok[BM];

    int tid = threadIdx.x;
    if (tid < BM) stok[tid] = perm[row0 + (tid < rows ? tid : 0)];
    __syncthreads();

    int lane = tid & 63, w = tid >> 6;
    int wr = w >> 1, wc = w & 1;
    int fr = lane & 15, g = lane >> 4;
    int lrow = lane >> 3;
    int schunk = (lane & 7) ^ lrow;                      // pre-swizzled source chunk
    int tokA[4];
    #pragma unroll
    for (int k = 0; k < 4; ++k) tokA[k] = stok[w * 32 + k * 8 + lrow];

    auto stage = [&](int buf, int k0, int c0) {
        #pragma unroll
        for (int k = 0; k < 4; ++k) {
            gload16(xb + (((size_t)tokA[k]) << 9) + k0 + schunk * 8, &smem[buf][0][w * 32 + k * 8][0]);
            gload16(W + (((size_t)(c0 + w * 32 + k * 8 + lrow)) << 9) + k0 + schunk * 8,
                    &smem[buf][1][w * 32 + k * 8][0]);
        }
    };

    f32x4 acc[4][4] = {};

    // LDS-staged epilogue into just-read buffer (8 vector stores/thread keeps vmcnt scheme sane)
    auto epilogue = [&](int buf, int c0) {
        u16* sT = &smem[buf][0][0][0];                   // 32 KB, logical [128][128] chunk-swizzled
        #pragma unroll
        for (int n = 0; n < 4; ++n) {
            int wcol = wc * 64 + n * 16 + fr;
            float bv_ = bias[c0 + wcol];
            #pragma unroll
            for (int m = 0; m < 4; ++m)
                #pragma unroll
                for (int i = 0; i < 4; ++i) {
                    int r = wr * 64 + m * 16 + g * 4 + i;
                    int ch = (wcol >> 3) ^ (r & 7);
                    sT[r * 128 + ch * 8 + (wcol & 7)] = f2bf((acc[m][n][i] + bv_) * qscale);
                }
        }
        asm volatile("s_waitcnt lgkmcnt(0)" ::: "memory");
        __builtin_amdgcn_s_barrier();
        int r = tid >> 1, h2 = tid & 1;
        if (r < rows) {
            int tok = stok[r], b = tok >> 9, s = tok & 511;
            int h = (c0 >> 6) + h2;
            u16* dst = outp + ((size_t)((b * NH + h) * NS + s) << 6);
            #pragma unroll
            for (int j2 = 0; j2 < 8; ++j2) {
                int ch = (h2 * 8 + j2) ^ (r & 7);
                *reinterpret_cast<short8*>(dst + j2 * 8) =
                    *reinterpret_cast<const short8*>(&sT[r * 128 + ch * 8]);
            }
        }
        asm volatile("s_waitcnt lgkmcnt(0)" ::: "memory");
        __builtin_amdgcn_s_barrier();
        #pragma unroll
        for (int m = 0; m < 4; ++m)
            #pragma unroll
            for (int n = 0; n < 4; ++n)
                acc[m][n] = (f32x4){0.f, 0.f, 0.f, 0.f};
    };

    stage(0, 0, colbase);
    #pragma unroll
    for (int j = 0; j < 16; ++j) {
        int cur = j & 1;
        if (j < 15) {
            int jn = j + 1;
            stage(cur ^ 1, (jn & 7) * BKK, colbase + (jn >> 3) * BN);
            asm volatile("s_waitcnt vmcnt(8)" ::: "memory");
        } else {
            asm volatile("s_waitcnt vmcnt(0)" ::: "memory");
        }
        __builtin_amdgcn_s_barrier();

        const char* Ab = (const char*)&smem[cur][0][0][0];
        const char* Bb = (const char*)&smem[cur][1][0][0];
        #pragma unroll
        for (int ks = 0; ks < 2; ++ks) {
            short8 af[4], bfr[4];
            #pragma unroll
            for (int m = 0; m < 4; ++m) {
                int r = wr * 64 + m * 16 + fr;
                af[m] = *reinterpret_cast<const short8*>(Ab + r * 128 + (((ks * 4 + g) ^ (r & 7)) << 4));
            }
            #pragma unroll
            for (int n = 0; n < 4; ++n) {
                int r = wc * 64 + n * 16 + fr;
                bfr[n] = *reinterpret_cast<const short8*>(Bb + r * 128 + (((ks * 4 + g) ^ (r & 7)) << 4));
            }
            #pragma unroll
            for (int m = 0; m < 4; ++m)
                #pragma unroll
                for (int n = 0; n < 4; ++n)
                    acc[m][n] = __builtin_amdgcn_mfma_f32_16x16x32_bf16(af[m], bfr[n], acc[m][n], 0, 0, 0);
        }
        asm volatile("s_waitcnt lgkmcnt(0)" ::: "memory");
        __builtin_amdgcn_s_barrier();

        if (j == 7) epilogue(1, colbase);        // cur==1 here; in-flight stage targets buf 0
    }
    epilogue(1, colbase + BN);                   // cur==1 at j=15 as well
}

// ================= V transpose: vb [bh][s][dk] -> vtb [bh][dk][s] =================
__global__ __launch_bounds__(256) void transp_v(const u16* __restrict__ vb, u16* __restrict__ vtb)
{
    int bh = blockIdx.y, s0 = blockIdx.x * 64;
    __shared__ __align__(16) u16 t[64][72];
    int tid = threadIdx.x;
    const u16* src = vb + ((size_t)bh << 15) + ((size_t)s0 << 6);
    #pragma unroll
    for (int it = 0; it < 2; ++it) {
        int idx = it * 256 + tid;
        int s = idx & 63, c = idx >> 6;
        short8 v = *reinterpret_cast<const short8*>(src + ((size_t)s << 6) + c * 8);
        #pragma unroll
        for (int j = 0; j < 8; ++j) t[c * 8 + j][s] = ((const u16*)&v)[j];
    }
    __syncthreads();
    u16* dst = vtb + ((size_t)bh << 15) + s0;
    #pragma unroll
    for (int it = 0; it < 2; ++it) {
        int idx = it * 256 + tid;
        int dk = idx >> 3, c = idx & 7;
        short8 v = *reinterpret_cast<const short8*>(&t[dk][c * 8]);
        *reinterpret_cast<short8*>(dst + (size_t)dk * NS + c * 8) = v;
    }
}

// ================= MFMA flash attention, swapped-QK^T wave-parallel softmax =================
__global__ __launch_bounds__(256) void attn_mfma(
    const u16* __restrict__ qb, const u16* __restrict__ kbf, const u16* __restrict__ vtb,
    const u64* __restrict__ maskb, u16* __restrict__ attb)
{
    int work = (blockIdx.x & 7) * 128 + (blockIdx.x >> 3);
    int bh = work >> 3, jq = work & 7;
    int b = bh >> 3, h = bh & 7;
    int q0 = jq * 64;
    int tid = threadIdx.x, lane = tid & 63, w = tid >> 6;
    int ln15 = lane & 15, g = lane >> 4;

    __shared__ __align__(16) u16 sK[64 * 64];
    __shared__ __align__(16) u16 sVt[64 * 64];
    __shared__ __align__(16) u16 sP[4 * 16 * 68];

    const u16* Qg = qb + ((size_t)(bh * NS + q0 + w * 16 + ln15) << 6);
    short8 aq0 = *reinterpret_cast<const short8*>(Qg + g * 8);
    short8 aq1 = *reinterpret_cast<const short8*>(Qg + 32 + g * 8);

    const u16* Kg = kbf + ((size_t)bh << 15);
    const u16* Vtg = vtb + ((size_t)bh << 15);
    int srow = tid >> 3, schunk = tid & 7;

    const u64* Mq = maskb + ((size_t)((b << 9) + q0 + w * 16 + ln15)) * 8;
    float mrun = -3.0e38f, lrun = 0.f;
    f32x4 acc_o[4] = {};

    short8 kpre0 = *reinterpret_cast<const short8*>(Kg + ((size_t)srow << 6) + schunk * 8);
    short8 kpre1 = *reinterpret_cast<const short8*>(Kg + ((size_t)(srow + 32) << 6) + schunk * 8);
    short8 vpre0 = *reinterpret_cast<const short8*>(Vtg + (size_t)srow * NS + schunk * 8);
    short8 vpre1 = *reinterpret_cast<const short8*>(Vtg + (size_t)(srow + 32) * NS + schunk * 8);

    char* sPw = (char*)sP + w * 16 * 136;

    for (int j = 0; j < 8; ++j) {
        __syncthreads();
        {
            int r2 = srow + 32;
            *reinterpret_cast<short8*>((char*)sK  + srow * 128 + ((schunk * 16) ^ ((srow & 7) << 4))) = kpre0;
            *reinterpret_cast<short8*>((char*)sK  + r2   * 128 + ((schunk * 16) ^ ((r2   & 7) << 4))) = kpre1;
            *reinterpret_cast<short8*>((char*)sVt + srow * 128 + ((schunk * 16) ^ ((srow & 7) << 4))) = vpre0;
            *reinterpret_cast<short8*>((char*)sVt + r2   * 128 + ((schunk * 16) ^ ((r2   & 7) << 4))) = vpre1;
        }
        if (j < 7) {
            int j1 = j + 1;
            kpre0 = *reinterpret_cast<const short8*>(Kg + ((size_t)(j1 * 64 + srow) << 6) + schunk * 8);
            kpre1 = *reinterpret_cast<const short8*>(Kg + ((size_t)(j1 * 64 + srow + 32) << 6) + schunk * 8);
            vpre0 = *reinterpret_cast<const short8*>(Vtg + (size_t)srow * NS + j1 * 64 + schunk * 8);
            vpre1 = *reinterpret_cast<const short8*>(Vtg + (size_t)(srow + 32) * NS + j1 * 64 + schunk * 8);
        }
        __syncthreads();

        f32x4 accs[4] = {};
        __builtin_amdgcn_s_setprio(1);
        #pragma unroll
        for (int ks = 0; ks < 2; ++ks) {
            short8 bq_ = ks ? aq1 : aq0;
            #pragma unroll
            for (int n = 0; n < 4; ++n) {
                int row = n * 16 + ln15;
                short8 kfrag = *reinterpret_cast<const short8*>(
                    (char*)sK + row * 128 + (((ks * 64) + g * 16) ^ ((row & 7) << 4)));
                accs[n] = __builtin_amdgcn_mfma_f32_16x16x32_bf16(kfrag, bq_, accs[n], 0, 0, 0);
            }
        }
        __builtin_amdgcn_s_setprio(0);

        u64 mw = Mq[j];
        float sv[4][4];
        float mx = -3.0e38f;
        #pragma unroll
        for (int n = 0; n < 4; ++n) {
            u32 b4 = (u32)(mw >> (n * 16 + g * 4)) & 15u;
            #pragma unroll
            for (int r = 0; r < 4; ++r) {
                float s = (b4 >> r) & 1u ? accs[n][r] : -1.0e9f;
                sv[n][r] = s;
                mx = fmaxf(mx, s);
            }
        }
        mx = fmaxf(mx, __shfl_xor(mx, 16));
        mx = fmaxf(mx, __shfl_xor(mx, 32));

        if (__any(mx > mrun + 8.f)) {
            float nm = fmaxf(mrun, mx);
            float sc = exp2f(mrun - nm);
            mrun = nm;
            lrun *= sc;
            #pragma unroll
            for (int i = 0; i < 4; ++i) {
                float si = __shfl(sc, g * 4 + i);
                #pragma unroll
                for (int n2 = 0; n2 < 4; ++n2) acc_o[n2][i] *= si;
            }
        }

        float ps = 0.f;
        #pragma unroll
        for (int n = 0; n < 4; ++n) {
            float p0 = exp2f(sv[n][0] - mrun), p1 = exp2f(sv[n][1] - mrun);
            float p2 = exp2f(sv[n][2] - mrun), p3 = exp2f(sv[n][3] - mrun);
            ps += (p0 + p1) + (p2 + p3);
            *reinterpret_cast<u32*>(sPw + ln15 * 136 + n * 32 + g * 8 + 0) = pk2(p0, p1);
            *reinterpret_cast<u32*>(sPw + ln15 * 136 + n * 32 + g * 8 + 4) = pk2(p2, p3);
        }
        ps += __shfl_xor(ps, 16);
        ps += __shfl_xor(ps, 32);
        lrun += ps;

        __builtin_amdgcn_s_setprio(1);
        #pragma unroll
        for (int ks = 0; ks < 2; ++ks) {
            short8 ap = *reinterpret_cast<const short8*>(sPw + ln15 * 136 + ks * 64 + g * 16);
            #pragma unroll
            for (int n2 = 0; n2 < 4; ++n2) {
                int row = n2 * 16 + ln15;
                short8 vfrag = *reinterpret_cast<const short8*>(
                    (char*)sVt + row * 128 + (((ks * 64) + g * 16) ^ ((row & 7) << 4)));
                acc_o[n2] = __builtin_amdgcn_mfma_f32_16x16x32_bf16(ap, vfrag, acc_o[n2], 0, 0, 0);
            }
        }
        __builtin_amdgcn_s_setprio(0);
    }

    float linv = 1.f / lrun;
    #pragma unroll
    for (int i = 0; i < 4; ++i) {
        float li = __shfl(linv, g * 4 + i);
        int q = q0 + w * 16 + g * 4 + i;
        #pragma unroll
        for (int n2 = 0; n2 < 4; ++n2) {
            attb[((size_t)((b << 9) + q) << 9) + (h << 6) + n2 * 16 + ln15] =
                f2bf(acc_o[n2][i] * li);
        }
    }
}

// ================= grouped out-proj GEMM + bias + residual(xb) -> bf16 hbuf =================
__global__ __launch_bounds__(256) void out_gemm(
    const u16* __restrict__ attb, const u16* __restrict__ Wat, const float* __restrict__ ba,
    const int* __restrict__ perm, const int* __restrict__ typeoff,
    const int* __restrict__ tile_type, const int* __restrict__ tile_row0, const int* __restrict__ ntiles,
    const u16* __restrict__ xb, u16* __restrict__ hbuf)
{
    int work = (blockIdx.x & 7) * 36 + (blockIdx.x >> 3);   // 288 = 8*36
    int tile = work >> 2;
    if (tile >= *ntiles) return;
    int t = tile_type[tile];
    int row0 = tile_row0[tile];
    int rows = typeoff[t + 1] - row0; if (rows > BM) rows = BM;
    int col0 = (work & 3) * BN;
    const u16* W = Wat + ((size_t)t << 18);
    const float* bias = ba + (t << 9);

    __shared__ __align__(16) u16 As[2][BM][BKK];
    __shared__ __align__(16) u16 Bs[2][BM][BKK];
    __shared__ int stok[BM];

    int tid = threadIdx.x;
    if (tid < BM) stok[tid] = perm[row0 + (tid < rows ? tid : 0)];
    __syncthreads();

    int lane = tid & 63, w = tid >> 6;
    int wr = w >> 1, wc = w & 1;
    int fr = lane & 15, g = lane >> 4;

    int lrow = lane >> 3;
    int schunk = (lane & 7) ^ lrow;
    int tokA[4];
    #pragma unroll
    for (int k = 0; k < 4; ++k) tokA[k] = stok[w * 32 + k * 8 + lrow];

    auto stage = [&](int buf, int k0) {
        #pragma unroll
        for (int k = 0; k < 4; ++k) {
            gload16(attb + (((size_t)tokA[k]) << 9) + k0 + schunk * 8, &As[buf][w * 32 + k * 8][0]);
            gload16(W + (((size_t)(col0 + w * 32 + k * 8 + lrow)) << 9) + k0 + schunk * 8,
                    &Bs[buf][w * 32 + k * 8][0]);
        }
    };

    f32x4 acc[4][4] = {};

    stage(0, 0);
    #pragma unroll
    for (int it = 0; it < 8; ++it) {
        int cur = it & 1;
        if (it < 7) {
            stage(cur ^ 1, (it + 1) * BKK);
            asm volatile("s_waitcnt vmcnt(8)" ::: "memory");
        } else {
            asm volatile("s_waitcnt vmcnt(0)" ::: "memory");
        }
        __builtin_amdgcn_s_barrier();

        const char* Ab = (const char*)As[cur];
        const char* Bb = (const char*)Bs[cur];
        #pragma unroll
        for (int ks = 0; ks < 2; ++ks) {
            short8 af[4], bfr[4];
            #pragma unroll
            for (int m = 0; m < 4; ++m) {
                int r = wr * 64 + m * 16 + fr;
                af[m] = *reinterpret_cast<const short8*>(Ab + r * 128 + (((ks * 4 + g) ^ (r & 7)) << 4));
            }
            #pragma unroll
            for (int n = 0; n < 4; ++n) {
                int r = wc * 64 + n * 16 + fr;
                bfr[n] = *reinterpret_cast<const short8*>(Bb + r * 128 + (((ks * 4 + g) ^ (r & 7)) << 4));
            }
            #pragma unroll
            for (int m = 0; m < 4; ++m)
                #pragma unroll
                for (int n = 0; n < 4; ++n)
                    acc[m][n] = __builtin_amdgcn_mfma_f32_16x16x32_bf16(af[m], bfr[n], acc[m][n], 0, 0, 0);
        }
        asm volatile("s_waitcnt lgkmcnt(0)" ::: "memory");
        __builtin_amdgcn_s_barrier();
    }

    int rbase = g << 2;
    #pragma unroll
    for (int n = 0; n < 4; ++n) {
        int c = col0 + wc * 64 + n * 16 + fr;
        float bv_ = bias[c];
        #pragma unroll
        for (int m = 0; m < 4; ++m) {
            #pragma unroll
            for (int i = 0; i < 4; ++i) {
                int r = wr * 64 + m * 16 + rbase + i;
                if (r < rows) {
                    int tok = stok[r];
                    size_t off = (size_t)tok * ND + c;
                    hbuf[off] = f2bf(acc[m][n][i] + bv_ + bf2f(xb[off]));
                }
            }
        }
    }
}

// ================= per-type LayerNorm (bf16 h input) =================
__global__ __launch_bounds__(256) void lnorm(
    const u16* __restrict__ hbuf, const int* __restrict__ xty,
    const float* __restrict__ gamma, const float* __restrict__ beta, float* __restrict__ out)
{
    int row = blockIdx.x * 4 + (threadIdx.x >> 6);
    int lane = threadIdx.x & 63;
    short8 v = *reinterpret_cast<const short8*>(hbuf + (size_t)row * ND + lane * 8);
    float f[8];
    float sum = 0.f, sq = 0.f;
    #pragma unroll
    for (int k = 0; k < 8; ++k) {
        f[k] = bf2f(((const u16*)&v)[k]);
        sum += f[k];
        sq += f[k] * f[k];
    }
    #pragma unroll
    for (int off = 32; off; off >>= 1) { sum += __shfl_xor(sum, off); sq += __shfl_xor(sq, off); }
    float mu = sum * (1.f / ND);
    float var = sq * (1.f / ND) - mu * mu;
    float is = rsqrtf(var + 1e-5f);
    int t = xty[row];
    const float4* g4 = reinterpret_cast<const float4*>(gamma + ((size_t)t << 9) + lane * 8);
    const float4* b4 = reinterpret_cast<const float4*>(beta + ((size_t)t << 9) + lane * 8);
    float4 g0 = g4[0], g1 = g4[1];
    float4 b0 = b4[0], b1 = b4[1];
    float4 o0, o1;
    o0.x = (f[0] - mu) * is * g0.x + b0.x;
    o0.y = (f[1] - mu) * is * g0.y + b0.y;
    o0.z = (f[2] - mu) * is * g0.z + b0.z;
    o0.w = (f[3] - mu) * is * g0.w + b0.w;
    o1.x = (f[4] - mu) * is * g1.x + b1.x;
    o1.y = (f[5] - mu) * is * g1.y + b1.y;
    o1.z = (f[6] - mu) * is * g1.z + b1.z;
    o1.w = (f[7] - mu) * is * g1.w + b1.w;
    float4* out4 = reinterpret_cast<float4*>(out + (size_t)row * ND + lane * 8);
    out4[0] = o0; out4[1] = o1;
}

extern "C" void kernel_launch(void* const* d_in, const int* in_sizes, int n_in,
                              void* d_out, int out_size, void* d_ws, size_t ws_size,
                              hipStream_t stream)
{
    const float* x     = (const float*)d_in[0];
    const int*   xty   = (const int*)d_in[1];
    const int*   mask  = (const int*)d_in[2];
    const float* Wq    = (const float*)d_in[3];
    const float* bq    = (const float*)d_in[4];
    const float* Wk    = (const float*)d_in[5];
    const float* bk    = (const float*)d_in[6];
    const float* Wv    = (const float*)d_in[7];
    const float* bv    = (const float*)d_in[8];
    const float* Wa    = (const float*)d_in[9];
    const float* ba    = (const float*)d_in[10];
    const float* gamma = (const float*)d_in[11];
    const float* beta  = (const float*)d_in[12];
    float* out = (float*)d_out;

    char* ws = (char*)d_ws;
    u16*   xb      = (u16*)(ws + 0);             //  8 MB
    u16*   Wqt     = (u16*)(ws + 8388608);       //  4 MB each
    u16*   Wkt     = (u16*)(ws + 12582912);
    u16*   Wvt     = (u16*)(ws + 16777216);
    u16*   Wat     = (u16*)(ws + 20971520);
    u16*   qb      = (u16*)(ws + 25165824);      //  8 MB (bf16, pre-scaled)
    u16*   kbf     = (u16*)(ws + 33554432);      //  8 MB
    u16*   vb      = (u16*)(ws + 41943040);      //  8 MB (V, [bh][s][dk])
    u16*   vtb     = (u16*)(ws + 50331648);      //  8 MB (V^T, [bh][dk][s])
    u16*   attb    = (u16*)(ws + 58720256);      //  8 MB
    u16*   hbuf    = (u16*)(ws + 67108864);      //  8 MB (bf16 residual h)
    u64*   maskb   = (u64*)(ws + 83886080);      // 512 KB
    int*   perm    = (int*)(ws + 84410368);      //  32 KB
    int*   typeoff = (int*)(ws + 84443136);
    int*   ttile   = (int*)(ws + 84443200);
    int*   trow    = (int*)(ws + 84443776);
    int*   ntiles  = (int*)(ws + 84444352);
    int*   scnt    = (int*)(ws + 84444480);      // 64*8 ints

    pre_all<<<dim3(7232), dim3(256), 0, stream>>>(x, xty, mask, Wq, Wk, Wv, Wa,
                                                  xb, Wqt, Wkt, Wvt, Wat, maskb, scnt);
    scatter_k<<<dim3(64), dim3(256), 0, stream>>>(xty, scnt, perm, typeoff, ttile, trow, ntiles);
    qkv_gemm<<<dim3(432), dim3(256), 0, stream>>>(xb, Wqt, Wkt, Wvt, bq, bk, bv,
                                                  perm, typeoff, ttile, trow, ntiles, qb, kbf, vb);
    transp_v<<<dim3(8, 128), dim3(256), 0, stream>>>(vb, vtb);
    attn_mfma<<<dim3(1024), dim3(256), 0, stream>>>(qb, kbf, vtb, maskb, attb);
    out_gemm<<<dim3(288), dim3(256), 0, stream>>>(attb, Wat, ba,
                                                  perm, typeoff, ttile, trow, ntiles, xb, hbuf);
    lnorm<<<dim3(2048), dim3(256), 0, stream>>>(hbuf, xty, gamma, beta, out);
}

// Round 8
// 248.103 us; speedup vs baseline: 1.0126x; 1.0126x over previous
//
#include <hip/hip_runtime.h>
#include <hip/hip_bf16.h>

typedef __attribute__((ext_vector_type(8))) short short8;
typedef __attribute__((ext_vector_type(4))) float f32x4;
typedef __attribute__((ext_vector_type(4))) unsigned short u16x4;
typedef unsigned short u16;
typedef unsigned int u32;
typedef unsigned long long u64;

#define NB 16
#define NS 512
#define ND 512
#define NH 8
#define NT 8
#define NDK 64
#define NN (NB*NS)
#define SCALE_LOG2E 0.18033688011112042f   // (1/sqrt(64)) * log2(e)
#define BM 128
#define BN 128
#define BKK 64

__device__ __forceinline__ u16 f2bf(float f) {
    __hip_bfloat16 h = __float2bfloat16(f);
    return *reinterpret_cast<u16*>(&h);
}
__device__ __forceinline__ float bf2f(u16 b) {
    u32 u = ((u32)b) << 16;
    return *reinterpret_cast<float*>(&u);
}
__device__ __forceinline__ u32 pk2(float lo, float hi) {
    return (u32)f2bf(lo) | ((u32)f2bf(hi) << 16);
}

typedef const __attribute__((address_space(1))) void* gas_t;
typedef __attribute__((address_space(3))) void* las_t;

__device__ __forceinline__ void gload16(const void* gsrc, void* ldst) {
    __builtin_amdgcn_global_load_lds((gas_t)gsrc, (las_t)ldst, 16, 0, 0);
}

// ================= fused preprocessing =================
__global__ __launch_bounds__(256) void pre_all(
    const float* __restrict__ x, const int* __restrict__ xty, const int* __restrict__ mask,
    const float* __restrict__ Wq, const float* __restrict__ Wk,
    const float* __restrict__ Wv, const float* __restrict__ Wa,
    u16* __restrict__ xb,
    u16* __restrict__ Wqt, u16* __restrict__ Wkt, u16* __restrict__ Wvt, u16* __restrict__ Wat,
    u64* __restrict__ maskb, int* __restrict__ scnt)
{
    __shared__ __align__(16) float tile[64][68];
    __shared__ int cnt[NT];
    int bid = blockIdx.x, tid = threadIdx.x;

    if (bid < 4096) {                           // ---- cvt_x ----
        int i = bid * 256 + tid;
        float4 v = reinterpret_cast<const float4*>(x)[i];
        u16x4 o;
        o.x = f2bf(v.x); o.y = f2bf(v.y); o.z = f2bf(v.z); o.w = f2bf(v.w);
        reinterpret_cast<u16x4*>(xb)[i] = o;
    } else if (bid < 6144) {                    // ---- cvt_w (transpose+convert) ----
        int wid = bid - 4096;
        int bx = wid & 7, by = (wid >> 3) & 7, bz = wid >> 6;
        int arr = bz >> 3, t = bz & 7;
        const float* W = (arr == 0 ? Wq : arr == 1 ? Wk : arr == 2 ? Wv : Wa) + ((size_t)t << 18);
        u16* O = (arr == 0 ? Wqt : arr == 1 ? Wkt : arr == 2 ? Wvt : Wat) + ((size_t)t << 18);
        int d0 = bx * 64, h0 = by * 64;
        int tx = tid & 15, ty = tid >> 4;
        #pragma unroll
        for (int i = 0; i < 4; ++i) {
            int r = ty + i * 16;
            float4 v = *reinterpret_cast<const float4*>(&W[(size_t)(d0 + r) * ND + h0 + tx * 4]);
            *reinterpret_cast<float4*>(&tile[r][tx * 4]) = v;
        }
        __syncthreads();
        #pragma unroll
        for (int i = 0; i < 4; ++i) {
            int r = ty + i * 16;
            u16x4 o;
            o.x = f2bf(tile[tx * 4 + 0][r]);
            o.y = f2bf(tile[tx * 4 + 1][r]);
            o.z = f2bf(tile[tx * 4 + 2][r]);
            o.w = f2bf(tile[tx * 4 + 3][r]);
            *reinterpret_cast<u16x4*>(&O[(size_t)(h0 + r) * ND + d0 + tx * 4]) = o;
        }
    } else if (bid < 7168) {                    // ---- pack_mask, grid-stride 16 ----
        int base = (bid - 6144) * 16;
        #pragma unroll
        for (int c = 0; c < 16; ++c) {
            int i = (base + c) * 256 + tid;
            int v = mask[i];
            u64 bal = __ballot(v != 0);
            if ((tid & 63) == 0) maskb[i >> 6] = bal;
        }
    } else {                                    // ---- type count, slice s ----
        int s = bid - 7168;
        if (tid < NT) cnt[tid] = 0;
        __syncthreads();
        if (tid < 128) atomicAdd(&cnt[xty[s * 128 + tid]], 1);
        __syncthreads();
        if (tid < NT) scnt[s * 8 + tid] = cnt[tid];
    }
}

// ================= scatter: build perm / typeoff / tile list =================
__global__ __launch_bounds__(256) void scatter_k(
    const int* __restrict__ xty, const int* __restrict__ scnt,
    int* __restrict__ perm, int* __restrict__ typeoff,
    int* __restrict__ tile_type, int* __restrict__ tile_row0, int* __restrict__ ntiles)
{
    __shared__ int base[NT], tot[NT];
    int s = blockIdx.x, tid = threadIdx.x;
    if (tid < NT) {
        int tt = 0;
        for (int ss = 0; ss < 64; ++ss) tt += scnt[ss * 8 + tid];
        tot[tid] = tt;
    }
    __syncthreads();
    if (tid < NT) {
        int off = 0;
        for (int u = 0; u < tid; ++u) off += tot[u];
        base[tid] = off;
    }
    __syncthreads();
    {
        int t = tid & 7;
        for (int ss = tid >> 3; ss < s; ss += 32) atomicAdd(&base[t], scnt[ss * 8 + t]);
    }
    __syncthreads();
    if (tid < 128) {
        int n = s * 128 + tid;
        int t = xty[n];
        int p = atomicAdd(&base[t], 1);
        perm[p] = n;
    }
    if (s == 0 && tid == 0) {
        int acc = 0, nt = 0;
        for (int t = 0; t < NT; ++t) {
            typeoff[t] = acc;
            int c = tot[t];
            for (int r = 0; r < c; r += BM) { tile_type[nt] = t; tile_row0[nt] = acc + r; ++nt; }
            acc += c;
        }
        typeoff[NT] = acc;
        *ntiles = nt;
    }
}

// ================= grouped GEMM qkv (r5 form): dbuf + counted vmcnt + end LDS epilogue =================
__global__ __launch_bounds__(256) void qkv_gemm(
    const u16* __restrict__ xb,
    const u16* __restrict__ Wqt, const u16* __restrict__ Wkt, const u16* __restrict__ Wvt,
    const float* __restrict__ bq, const float* __restrict__ bk, const float* __restrict__ bv,
    const int* __restrict__ perm, const int* __restrict__ typeoff,
    const int* __restrict__ tile_type, const int* __restrict__ tile_row0, const int* __restrict__ ntiles,
    u16* __restrict__ qb, u16* __restrict__ kbf, u16* __restrict__ vb)
{
    int work = (blockIdx.x & 7) * 108 + (blockIdx.x >> 3);  // XCD swizzle (864 = 8*108)
    int tile = work / 12, pc = work % 12;
    if (tile >= *ntiles) return;
    int t = tile_type[tile];
    int row0 = tile_row0[tile];
    int rows = typeoff[t + 1] - row0; if (rows > BM) rows = BM;
    int proj = pc >> 2;
    int col0 = (pc & 3) * BN;
    const u16* W = (proj == 0 ? Wqt : proj == 1 ? Wkt : Wvt) + ((size_t)t << 18);
    const float* bias = (proj == 0 ? bq : proj == 1 ? bk : bv) + (t << 9);
    u16* outp = proj == 0 ? qb : proj == 1 ? kbf : vb;
    float qscale = proj == 0 ? SCALE_LOG2E : 1.f;

    __shared__ __align__(16) u16 smem[2][2][BM][BKK];   // 64 KB
    __shared__ int stok[BM];
    auto As = smem[0]; auto Bs = smem[1];

    int tid = threadIdx.x;
    if (tid < BM) stok[tid] = perm[row0 + (tid < rows ? tid : 0)];
    __syncthreads();

    int lane = tid & 63, w = tid >> 6;
    int wr = w >> 1, wc = w & 1;
    int fr = lane & 15, g = lane >> 4;

    int lrow = lane >> 3;
    int schunk = (lane & 7) ^ lrow;             // pre-swizzled source chunk (16B units)
    int tokA[4];
    #pragma unroll
    for (int k = 0; k < 4; ++k) tokA[k] = stok[w * 32 + k * 8 + lrow];

    auto stage = [&](int buf, int k0) {
        #pragma unroll
        for (int k = 0; k < 4; ++k) {
            gload16(xb + (((size_t)tokA[k]) << 9) + k0 + schunk * 8, &As[buf][w * 32 + k * 8][0]);
            gload16(W + (((size_t)(col0 + w * 32 + k * 8 + lrow)) << 9) + k0 + schunk * 8,
                    &Bs[buf][w * 32 + k * 8][0]);
        }
    };

    f32x4 acc[4][4] = {};

    stage(0, 0);
    #pragma unroll
    for (int it = 0; it < 8; ++it) {
        int cur = it & 1;
        if (it < 7) {
            stage(cur ^ 1, (it + 1) * BKK);
            asm volatile("s_waitcnt vmcnt(8)" ::: "memory");
        } else {
            asm volatile("s_waitcnt vmcnt(0)" ::: "memory");
        }
        __builtin_amdgcn_s_barrier();

        const char* Ab = (const char*)As[cur];
        const char* Bb = (const char*)Bs[cur];
        #pragma unroll
        for (int ks = 0; ks < 2; ++ks) {
            short8 af[4], bfr[4];
            #pragma unroll
            for (int m = 0; m < 4; ++m) {
                int r = wr * 64 + m * 16 + fr;
                af[m] = *reinterpret_cast<const short8*>(Ab + r * 128 + (((ks * 4 + g) ^ (r & 7)) << 4));
            }
            #pragma unroll
            for (int n = 0; n < 4; ++n) {
                int r = wc * 64 + n * 16 + fr;
                bfr[n] = *reinterpret_cast<const short8*>(Bb + r * 128 + (((ks * 4 + g) ^ (r & 7)) << 4));
            }
            #pragma unroll
            for (int m = 0; m < 4; ++m)
                #pragma unroll
                for (int n = 0; n < 4; ++n)
                    acc[m][n] = __builtin_amdgcn_mfma_f32_16x16x32_bf16(af[m], bfr[n], acc[m][n], 0, 0, 0);
        }
        asm volatile("s_waitcnt lgkmcnt(0)" ::: "memory");
        __builtin_amdgcn_s_barrier();
    }

    // epilogue: stage tile in LDS (reuse smem), store full-line coalesced per token
    u16 (*sT)[136] = reinterpret_cast<u16 (*)[136]>(&smem[0][0][0][0]);
    #pragma unroll
    for (int n = 0; n < 4; ++n) {
        int col = wc * 64 + n * 16 + fr;
        float bv_ = bias[col0 + col];
        #pragma unroll
        for (int m = 0; m < 4; ++m)
            #pragma unroll
            for (int i = 0; i < 4; ++i)
                sT[wr * 64 + m * 16 + g * 4 + i][col] = f2bf((acc[m][n][i] + bv_) * qscale);
    }
    __syncthreads();
    int r = tid >> 1, half = tid & 1;
    if (r < rows) {
        int tok = stok[r], b = tok >> 9, s = tok & 511;
        int h = (col0 >> 6) + half;
        u16* dst = outp + ((size_t)((b * NH + h) * NS + s) << 6);
        #pragma unroll
        for (int j = 0; j < 8; ++j)
            *reinterpret_cast<short8*>(dst + j * 8) =
                *reinterpret_cast<const short8*>(&sT[r][half * 64 + j * 8]);
    }
}

// ================= V transpose: vb [bh][s][dk] -> vtb [bh][dk][s] =================
__global__ __launch_bounds__(256) void transp_v(const u16* __restrict__ vb, u16* __restrict__ vtb)
{
    int bh = blockIdx.y, s0 = blockIdx.x * 64;
    __shared__ __align__(16) u16 t[64][72];
    int tid = threadIdx.x;
    const u16* src = vb + ((size_t)bh << 15) + ((size_t)s0 << 6);
    #pragma unroll
    for (int it = 0; it < 2; ++it) {
        int idx = it * 256 + tid;
        int s = idx & 63, c = idx >> 6;
        short8 v = *reinterpret_cast<const short8*>(src + ((size_t)s << 6) + c * 8);
        #pragma unroll
        for (int j = 0; j < 8; ++j) t[c * 8 + j][s] = ((const u16*)&v)[j];
    }
    __syncthreads();
    u16* dst = vtb + ((size_t)bh << 15) + s0;
    #pragma unroll
    for (int it = 0; it < 2; ++it) {
        int idx = it * 256 + tid;
        int dk = idx >> 3, c = idx & 7;
        short8 v = *reinterpret_cast<const short8*>(&t[dk][c * 8]);
        *reinterpret_cast<short8*>(dst + (size_t)dk * NS + c * 8) = v;
    }
}

// ================= MFMA flash attention: swapped QK^T + key-permuted sVt (in-reg P) =================
__global__ __launch_bounds__(256) void attn_mfma(
    const u16* __restrict__ qb, const u16* __restrict__ kbf, const u16* __restrict__ vtb,
    const u64* __restrict__ maskb, u16* __restrict__ attb)
{
    int work = (blockIdx.x & 7) * 128 + (blockIdx.x >> 3);
    int bh = work >> 3, jq = work & 7;
    int b = bh >> 3, h = bh & 7;
    int q0 = jq * 64;
    int tid = threadIdx.x, lane = tid & 63, w = tid >> 6;
    int ln15 = lane & 15, g = lane >> 4;

    __shared__ __align__(16) u16 sK[64 * 64];    // [key][dk], XOR-swizzled
    __shared__ __align__(16) u16 sVt[64 * 64];   // [dk][key-permuted], XOR-swizzled

    const u16* Qg = qb + ((size_t)(bh * NS + q0 + w * 16 + ln15) << 6);
    short8 aq0 = *reinterpret_cast<const short8*>(Qg + g * 8);
    short8 aq1 = *reinterpret_cast<const short8*>(Qg + 32 + g * 8);

    const u16* Kg = kbf + ((size_t)bh << 15);    // [s][dk]
    const u16* Vtg = vtb + ((size_t)bh << 15);   // [dk][s]
    int srow = tid >> 3, schunk = tid & 7;

    // V permutation constants (per thread): key = schunk*8 + j'
    int vks = schunk >> 2, vhalf = (schunk >> 1) & 1, vg0 = (schunk & 1) * 2;
    int vchunk0 = vks * 4 + vg0;                 // j' 0..3
    int vchunk1 = vchunk0 + 1;                   // j' 4..7

    const u64* Mq = maskb + ((size_t)((b << 9) + q0 + w * 16 + ln15)) * 8;
    float mrun = -3.0e38f, lrun = 0.f;
    f32x4 acc_o[4] = {};

    short8 kpre0 = *reinterpret_cast<const short8*>(Kg + ((size_t)srow << 6) + schunk * 8);
    short8 kpre1 = *reinterpret_cast<const short8*>(Kg + ((size_t)(srow + 32) << 6) + schunk * 8);
    short8 vpre0 = *reinterpret_cast<const short8*>(Vtg + (size_t)srow * NS + schunk * 8);
    short8 vpre1 = *reinterpret_cast<const short8*>(Vtg + (size_t)(srow + 32) * NS + schunk * 8);

    for (int j = 0; j < 8; ++j) {
        __syncthreads();
        {
            int r2 = srow + 32;
            *reinterpret_cast<short8*>((char*)sK + srow * 128 + ((schunk * 16) ^ ((srow & 7) << 4))) = kpre0;
            *reinterpret_cast<short8*>((char*)sK + r2   * 128 + ((schunk * 16) ^ ((r2   & 7) << 4))) = kpre1;
            u16x4 vlo0 = { (u16)vpre0[0], (u16)vpre0[1], (u16)vpre0[2], (u16)vpre0[3] };
            u16x4 vhi0 = { (u16)vpre0[4], (u16)vpre0[5], (u16)vpre0[6], (u16)vpre0[7] };
            u16x4 vlo1 = { (u16)vpre1[0], (u16)vpre1[1], (u16)vpre1[2], (u16)vpre1[3] };
            u16x4 vhi1 = { (u16)vpre1[4], (u16)vpre1[5], (u16)vpre1[6], (u16)vpre1[7] };
            *reinterpret_cast<u16x4*>((char*)sVt + srow * 128 + (((vchunk0) ^ (srow & 7)) << 4) + vhalf * 8) = vlo0;
            *reinterpret_cast<u16x4*>((char*)sVt + srow * 128 + (((vchunk1) ^ (srow & 7)) << 4) + vhalf * 8) = vhi0;
            *reinterpret_cast<u16x4*>((char*)sVt + r2 * 128 + (((vchunk0) ^ (r2 & 7)) << 4) + vhalf * 8) = vlo1;
            *reinterpret_cast<u16x4*>((char*)sVt + r2 * 128 + (((vchunk1) ^ (r2 & 7)) << 4) + vhalf * 8) = vhi1;
        }
        if (j < 7) {
            int j1 = j + 1;
            kpre0 = *reinterpret_cast<const short8*>(Kg + ((size_t)(j1 * 64 + srow) << 6) + schunk * 8);
            kpre1 = *reinterpret_cast<const short8*>(Kg + ((size_t)(j1 * 64 + srow + 32) << 6) + schunk * 8);
            vpre0 = *reinterpret_cast<const short8*>(Vtg + (size_t)srow * NS + j1 * 64 + schunk * 8);
            vpre1 = *reinterpret_cast<const short8*>(Vtg + (size_t)(srow + 32) * NS + j1 * 64 + schunk * 8);
        }
        __syncthreads();

        // swapped QK^T: lane holds S[key = n*16 + g*4 + r][q = ln15]
        f32x4 accs[4] = {};
        __builtin_amdgcn_s_setprio(1);
        #pragma unroll
        for (int ks = 0; ks < 2; ++ks) {
            short8 bq_ = ks ? aq1 : aq0;
            #pragma unroll
            for (int n = 0; n < 4; ++n) {
                int row = n * 16 + ln15;
                short8 kfrag = *reinterpret_cast<const short8*>(
                    (char*)sK + row * 128 + (((ks * 64) + g * 16) ^ ((row & 7) << 4)));
                accs[n] = __builtin_amdgcn_mfma_f32_16x16x32_bf16(kfrag, bq_, accs[n], 0, 0, 0);
            }
        }
        __builtin_amdgcn_s_setprio(0);

        // wave-parallel online softmax: one q per lane
        u64 mw = Mq[j];
        float sv[4][4];
        float mx = -3.0e38f;
        #pragma unroll
        for (int n = 0; n < 4; ++n) {
            u32 b4 = (u32)(mw >> (n * 16 + g * 4)) & 15u;
            #pragma unroll
            for (int r = 0; r < 4; ++r) {
                float s = (b4 >> r) & 1u ? accs[n][r] : -1.0e9f;
                sv[n][r] = s;
                mx = fmaxf(mx, s);
            }
        }
        mx = fmaxf(mx, __shfl_xor(mx, 16));
        mx = fmaxf(mx, __shfl_xor(mx, 32));

        if (__any(mx > mrun + 8.f)) {            // defer-max (T13)
            float nm = fmaxf(mrun, mx);
            float sc = exp2f(mrun - nm);
            mrun = nm;
            lrun *= sc;
            #pragma unroll
            for (int i = 0; i < 4; ++i) {
                float si = __shfl(sc, g * 4 + i);
                #pragma unroll
                for (int n2 = 0; n2 < 4; ++n2) acc_o[n2][i] *= si;
            }
        }

        float p[4][4];
        float ps = 0.f;
        #pragma unroll
        for (int n = 0; n < 4; ++n) {
            #pragma unroll
            for (int r = 0; r < 4; ++r) {
                p[n][r] = exp2f(sv[n][r] - mrun);
                ps += p[n][r];
            }
        }
        ps += __shfl_xor(ps, 16);
        ps += __shfl_xor(ps, 32);
        lrun += ps;

        // PV: A-operand packed fully in-register (keys permuted in sVt to match)
        __builtin_amdgcn_s_setprio(1);
        #pragma unroll
        for (int ks = 0; ks < 2; ++ks) {
            short8 ap;
            u32* apw = reinterpret_cast<u32*>(&ap);
            apw[0] = pk2(p[ks * 2][0], p[ks * 2][1]);
            apw[1] = pk2(p[ks * 2][2], p[ks * 2][3]);
            apw[2] = pk2(p[ks * 2 + 1][0], p[ks * 2 + 1][1]);
            apw[3] = pk2(p[ks * 2 + 1][2], p[ks * 2 + 1][3]);
            #pragma unroll
            for (int n2 = 0; n2 < 4; ++n2) {
                int row = n2 * 16 + ln15;
                short8 vfrag = *reinterpret_cast<const short8*>(
                    (char*)sVt + row * 128 + (((ks * 64) + g * 16) ^ ((row & 7) << 4)));
                acc_o[n2] = __builtin_amdgcn_mfma_f32_16x16x32_bf16(ap, vfrag, acc_o[n2], 0, 0, 0);
            }
        }
        __builtin_amdgcn_s_setprio(0);
    }

    float linv = 1.f / lrun;
    #pragma unroll
    for (int i = 0; i < 4; ++i) {
        float li = __shfl(linv, g * 4 + i);
        int q = q0 + w * 16 + g * 4 + i;
        #pragma unroll
        for (int n2 = 0; n2 < 4; ++n2) {
            attb[((size_t)((b << 9) + q) << 9) + (h << 6) + n2 * 16 + ln15] =
                f2bf(acc_o[n2][i] * li);
        }
    }
}

// ================= grouped out-proj GEMM + bias + residual(xb) -> bf16 hbuf =================
__global__ __launch_bounds__(256) void out_gemm(
    const u16* __restrict__ attb, const u16* __restrict__ Wat, const float* __restrict__ ba,
    const int* __restrict__ perm, const int* __restrict__ typeoff,
    const int* __restrict__ tile_type, const int* __restrict__ tile_row0, const int* __restrict__ ntiles,
    const u16* __restrict__ xb, u16* __restrict__ hbuf)
{
    int work = (blockIdx.x & 7) * 36 + (blockIdx.x >> 3);   // 288 = 8*36
    int tile = work >> 2;
    if (tile >= *ntiles) return;
    int t = tile_type[tile];
    int row0 = tile_row0[tile];
    int rows = typeoff[t + 1] - row0; if (rows > BM) rows = BM;
    int col0 = (work & 3) * BN;
    const u16* W = Wat + ((size_t)t << 18);
    const float* bias = ba + (t << 9);

    __shared__ __align__(16) u16 As[2][BM][BKK];
    __shared__ __align__(16) u16 Bs[2][BM][BKK];
    __shared__ int stok[BM];

    int tid = threadIdx.x;
    if (tid < BM) stok[tid] = perm[row0 + (tid < rows ? tid : 0)];
    __syncthreads();

    int lane = tid & 63, w = tid >> 6;
    int wr = w >> 1, wc = w & 1;
    int fr = lane & 15, g = lane >> 4;

    int lrow = lane >> 3;
    int schunk = (lane & 7) ^ lrow;
    int tokA[4];
    #pragma unroll
    for (int k = 0; k < 4; ++k) tokA[k] = stok[w * 32 + k * 8 + lrow];

    auto stage = [&](int buf, int k0) {
        #pragma unroll
        for (int k = 0; k < 4; ++k) {
            gload16(attb + (((size_t)tokA[k]) << 9) + k0 + schunk * 8, &As[buf][w * 32 + k * 8][0]);
            gload16(W + (((size_t)(col0 + w * 32 + k * 8 + lrow)) << 9) + k0 + schunk * 8,
                    &Bs[buf][w * 32 + k * 8][0]);
        }
    };

    f32x4 acc[4][4] = {};

    stage(0, 0);
    #pragma unroll
    for (int it = 0; it < 8; ++it) {
        int cur = it & 1;
        if (it < 7) {
            stage(cur ^ 1, (it + 1) * BKK);
            asm volatile("s_waitcnt vmcnt(8)" ::: "memory");
        } else {
            asm volatile("s_waitcnt vmcnt(0)" ::: "memory");
        }
        __builtin_amdgcn_s_barrier();

        const char* Ab = (const char*)As[cur];
        const char* Bb = (const char*)Bs[cur];
        #pragma unroll
        for (int ks = 0; ks < 2; ++ks) {
            short8 af[4], bfr[4];
            #pragma unroll
            for (int m = 0; m < 4; ++m) {
                int r = wr * 64 + m * 16 + fr;
                af[m] = *reinterpret_cast<const short8*>(Ab + r * 128 + (((ks * 4 + g) ^ (r & 7)) << 4));
            }
            #pragma unroll
            for (int n = 0; n < 4; ++n) {
                int r = wc * 64 + n * 16 + fr;
                bfr[n] = *reinterpret_cast<const short8*>(Bb + r * 128 + (((ks * 4 + g) ^ (r & 7)) << 4));
            }
            #pragma unroll
            for (int m = 0; m < 4; ++m)
                #pragma unroll
                for (int n = 0; n < 4; ++n)
                    acc[m][n] = __builtin_amdgcn_mfma_f32_16x16x32_bf16(af[m], bfr[n], acc[m][n], 0, 0, 0);
        }
        asm volatile("s_waitcnt lgkmcnt(0)" ::: "memory");
        __builtin_amdgcn_s_barrier();
    }

    int rbase = g << 2;
    #pragma unroll
    for (int n = 0; n < 4; ++n) {
        int c = col0 + wc * 64 + n * 16 + fr;
        float bv_ = bias[c];
        #pragma unroll
        for (int m = 0; m < 4; ++m) {
            #pragma unroll
            for (int i = 0; i < 4; ++i) {
                int r = wr * 64 + m * 16 + rbase + i;
                if (r < rows) {
                    int tok = stok[r];
                    size_t off = (size_t)tok * ND + c;
                    hbuf[off] = f2bf(acc[m][n][i] + bv_ + bf2f(xb[off]));
                }
            }
        }
    }
}

// ================= per-type LayerNorm (bf16 h input) =================
__global__ __launch_bounds__(256) void lnorm(
    const u16* __restrict__ hbuf, const int* __restrict__ xty,
    const float* __restrict__ gamma, const float* __restrict__ beta, float* __restrict__ out)
{
    int row = blockIdx.x * 4 + (threadIdx.x >> 6);
    int lane = threadIdx.x & 63;
    short8 v = *reinterpret_cast<const short8*>(hbuf + (size_t)row * ND + lane * 8);
    float f[8];
    float sum = 0.f, sq = 0.f;
    #pragma unroll
    for (int k = 0; k < 8; ++k) {
        f[k] = bf2f(((const u16*)&v)[k]);
        sum += f[k];
        sq += f[k] * f[k];
    }
    #pragma unroll
    for (int off = 32; off; off >>= 1) { sum += __shfl_xor(sum, off); sq += __shfl_xor(sq, off); }
    float mu = sum * (1.f / ND);
    float var = sq * (1.f / ND) - mu * mu;
    float is = rsqrtf(var + 1e-5f);
    int t = xty[row];
    const float4* g4 = reinterpret_cast<const float4*>(gamma + ((size_t)t << 9) + lane * 8);
    const float4* b4 = reinterpret_cast<const float4*>(beta + ((size_t)t << 9) + lane * 8);
    float4 g0 = g4[0], g1 = g4[1];
    float4 b0 = b4[0], b1 = b4[1];
    float4 o0, o1;
    o0.x = (f[0] - mu) * is * g0.x + b0.x;
    o0.y = (f[1] - mu) * is * g0.y + b0.y;
    o0.z = (f[2] - mu) * is * g0.z + b0.z;
    o0.w = (f[3] - mu) * is * g0.w + b0.w;
    o1.x = (f[4] - mu) * is * g1.x + b1.x;
    o1.y = (f[5] - mu) * is * g1.y + b1.y;
    o1.z = (f[6] - mu) * is * g1.z + b1.z;
    o1.w = (f[7] - mu) * is * g1.w + b1.w;
    float4* out4 = reinterpret_cast<float4*>(out + (size_t)row * ND + lane * 8);
    out4[0] = o0; out4[1] = o1;
}

extern "C" void kernel_launch(void* const* d_in, const int* in_sizes, int n_in,
                              void* d_out, int out_size, void* d_ws, size_t ws_size,
                              hipStream_t stream)
{
    const float* x     = (const float*)d_in[0];
    const int*   xty   = (const int*)d_in[1];
    const int*   mask  = (const int*)d_in[2];
    const float* Wq    = (const float*)d_in[3];
    const float* bq    = (const float*)d_in[4];
    const float* Wk    = (const float*)d_in[5];
    const float* bk    = (const float*)d_in[6];
    const float* Wv    = (const float*)d_in[7];
    const float* bv    = (const float*)d_in[8];
    const float* Wa    = (const float*)d_in[9];
    const float* ba    = (const float*)d_in[10];
    const float* gamma = (const float*)d_in[11];
    const float* beta  = (const float*)d_in[12];
    float* out = (float*)d_out;

    char* ws = (char*)d_ws;
    u16*   xb      = (u16*)(ws + 0);             //  8 MB
    u16*   Wqt     = (u16*)(ws + 8388608);       //  4 MB each
    u16*   Wkt     = (u16*)(ws + 12582912);
    u16*   Wvt     = (u16*)(ws + 16777216);
    u16*   Wat     = (u16*)(ws + 20971520);
    u16*   qb      = (u16*)(ws + 25165824);      //  8 MB (bf16, pre-scaled)
    u16*   kbf     = (u16*)(ws + 33554432);      //  8 MB
    u16*   vb      = (u16*)(ws + 41943040);      //  8 MB (V, [bh][s][dk])
    u16*   vtb     = (u16*)(ws + 50331648);      //  8 MB (V^T, [bh][dk][s])
    u16*   attb    = (u16*)(ws + 58720256);      //  8 MB
    u16*   hbuf    = (u16*)(ws + 67108864);      //  8 MB (bf16 residual h)
    u64*   maskb   = (u64*)(ws + 83886080);      // 512 KB
    int*   perm    = (int*)(ws + 84410368);      //  32 KB
    int*   typeoff = (int*)(ws + 84443136);
    int*   ttile   = (int*)(ws + 84443200);
    int*   trow    = (int*)(ws + 84443776);
    int*   ntiles  = (int*)(ws + 84444352);
    int*   scnt    = (int*)(ws + 84444480);      // 64*8 ints

    pre_all<<<dim3(7232), dim3(256), 0, stream>>>(x, xty, mask, Wq, Wk, Wv, Wa,
                                                  xb, Wqt, Wkt, Wvt, Wat, maskb, scnt);
    scatter_k<<<dim3(64), dim3(256), 0, stream>>>(xty, scnt, perm, typeoff, ttile, trow, ntiles);
    qkv_gemm<<<dim3(864), dim3(256), 0, stream>>>(xb, Wqt, Wkt, Wvt, bq, bk, bv,
                                                  perm, typeoff, ttile, trow, ntiles, qb, kbf, vb);
    transp_v<<<dim3(8, 128), dim3(256), 0, stream>>>(vb, vtb);
    attn_mfma<<<dim3(1024), dim3(256), 0, stream>>>(qb, kbf, vtb, maskb, attb);
    out_gemm<<<dim3(288), dim3(256), 0, stream>>>(attb, Wat, ba,
                                                  perm, typeoff, ttile, trow, ntiles, xb, hbuf);
    lnorm<<<dim3(2048), dim3(256), 0, stream>>>(hbuf, xty, gamma, beta, out);
}